// Round 3
// baseline (352.239 us; speedup 1.0000x reference)
//
#include <hip/hip_runtime.h>

constexpr int Bn = 8, Cn = 3, Hn = 720, Wn = 1280;
constexpr int HW = Hn * Wn;
constexpr long long NTOT = (long long)Bn * Cn * HW;     // 22,118,400

constexpr int TR   = 4;               // rows per block tile
constexpr int YT   = Hn / TR;         // 180 tiles per batch image
constexpr int NWG  = Bn * YT;         // 1440 blocks (8 XCDs x 180)
constexpr int GPR  = Wn / 4;          // 320 float4 groups per row
constexpr int ITER = (TR * GPR) / 256; // 5 iterations per block

typedef float f4 __attribute__((ext_vector_type(4)));

__device__ __forceinline__ void mk_coords(float xf, float yf,
                                          int& i00, int& i01, int& i10, int& i11,
                                          float& wx, float& wy) {
    xf = fminf(fmaxf(xf, 0.f), (float)(Wn - 1));
    yf = fminf(fmaxf(yf, 0.f), (float)(Hn - 1));
    const float x0f = floorf(xf), y0f = floorf(yf);
    wx = xf - x0f; wy = yf - y0f;
    const int x0 = (int)x0f, y0 = (int)y0f;
    const int x1 = min(x0 + 1, Wn - 1), y1 = min(y0 + 1, Hn - 1);
    i00 = y0 * Wn + x0; i01 = y0 * Wn + x1;
    i10 = y1 * Wn + x0; i11 = y1 * Wn + x1;
}

__device__ __forceinline__ float bilin(const float* __restrict__ base,
                                       int i00, int i01, int i10, int i11,
                                       float wx, float wy) {
    const float v00 = base[i00], v01 = base[i01];
    const float v10 = base[i10], v11 = base[i11];
    const float top = fmaf(wx, v01 - v00, v00);
    const float bot = fmaf(wx, v11 - v10, v10);
    return fmaf(wy, bot - top, top);
}

__global__ __launch_bounds__(256) void warp_loss_kernel(
        const float* __restrict__ L, const float* __restrict__ R,
        const float* __restrict__ Flm, const float* __restrict__ Frm,
        const float* __restrict__ G, double* __restrict__ accum) {
    const int bid = blockIdx.x;
    // XCD-bijective swizzle: XCD k (= bid%8) owns batch image k entirely.
    const int swz = (bid & 7) * (NWG / 8) + (bid >> 3);
    const int b   = swz / YT;
    const int yt  = swz - b * YT;

    const float* __restrict__ Lb = L + (size_t)b * Cn * HW;
    const float* __restrict__ Rb = R + (size_t)b * Cn * HW;
    const float* __restrict__ Gb = G + (size_t)b * Cn * HW;
    const float* __restrict__ fl = Flm + (size_t)b * 2 * HW;
    const float* __restrict__ fr = Frm + (size_t)b * 2 * HW;

    float local = 0.f;
    for (int t = 0; t < ITER; ++t) {
        const int gid = t * 256 + (int)threadIdx.x;
        const int r   = gid / GPR;
        const int g   = gid - r * GPR;
        const int y   = yt * TR + r;
        const int x0  = g * 4;
        const int p   = y * Wn + x0;

        // read-once streams: nontemporal so L2 keeps gather lines instead
        const f4 flx = __builtin_nontemporal_load((const f4*)(fl + p));
        const f4 fly = __builtin_nontemporal_load((const f4*)(fl + HW + p));
        const f4 frx = __builtin_nontemporal_load((const f4*)(fr + p));
        const f4 fry = __builtin_nontemporal_load((const f4*)(fr + HW + p));

        int   li[4][4], ri[4][4];
        float lwx[4], lwy[4], rwx[4], rwy[4];
        #pragma unroll
        for (int j = 0; j < 4; ++j) {
            mk_coords((float)(x0 + j) + flx[j], (float)y + fly[j],
                      li[j][0], li[j][1], li[j][2], li[j][3], lwx[j], lwy[j]);
            mk_coords((float)(x0 + j) + frx[j], (float)y + fry[j],
                      ri[j][0], ri[j][1], ri[j][2], ri[j][3], rwx[j], rwy[j]);
        }
        #pragma unroll
        for (int c = 0; c < Cn; ++c) {
            const f4 gv = __builtin_nontemporal_load((const f4*)(Gb + c * HW + p));
            const float* __restrict__ Lc = Lb + c * HW;
            const float* __restrict__ Rc = Rb + c * HW;
            #pragma unroll
            for (int j = 0; j < 4; ++j) {
                const float sL = bilin(Lc, li[j][0], li[j][1], li[j][2], li[j][3], lwx[j], lwy[j]);
                const float sR = bilin(Rc, ri[j][0], ri[j][1], ri[j][2], ri[j][3], rwx[j], rwy[j]);
                const float gg = gv[j];
                local += fabsf(sL - gg) + fabsf(sR - gg);
            }
        }
    }

    // wave(64) shuffle reduce, then cross-wave via LDS, one f64 atomic per block
    #pragma unroll
    for (int off = 32; off > 0; off >>= 1)
        local += __shfl_down(local, off, 64);

    __shared__ float wsum[4];
    const int lane = threadIdx.x & 63;
    const int wid  = threadIdx.x >> 6;
    if (lane == 0) wsum[wid] = local;
    __syncthreads();
    if (threadIdx.x == 0) {
        const float s = wsum[0] + wsum[1] + wsum[2] + wsum[3];
        atomicAdd(accum, (double)s);
    }
}

__global__ void finalize_kernel(const double* __restrict__ accum,
                                float* __restrict__ out) {
    out[0] = (float)(accum[0] / (double)NTOT);
}

extern "C" void kernel_launch(void* const* d_in, const int* in_sizes, int n_in,
                              void* d_out, int out_size, void* d_ws, size_t ws_size,
                              hipStream_t stream) {
    const float* L   = (const float*)d_in[0];
    const float* R   = (const float*)d_in[1];
    const float* flm = (const float*)d_in[2];
    const float* frm = (const float*)d_in[3];
    const float* gt  = (const float*)d_in[4];
    double* accum = (double*)d_ws;

    (void)hipMemsetAsync(accum, 0, sizeof(double), stream);
    warp_loss_kernel<<<NWG, 256, 0, stream>>>(L, R, flm, frm, gt, accum);
    finalize_kernel<<<1, 1, 0, stream>>>(accum, (float*)d_out);
}

// Round 4
// 192.141 us; speedup vs baseline: 1.8332x; 1.8332x over previous
//
#include <hip/hip_runtime.h>

constexpr int Bn = 8, Cn = 3, Hn = 720, Wn = 1280;
constexpr int HW = Hn * Wn;                    // 921600 px per image
constexpr long long NTOT = (long long)Bn * Cn * HW;

constexpr int BLK  = 256;
constexpr int NBX  = 360;                      // blocks per XCD (= per batch)
constexpr int NWG  = 8 * NBX;                  // 2880 blocks
constexpr int ITER = HW / (NBX * BLK);         // 10 iterations, exact

__device__ __forceinline__ void mk_coords(float xf, float yf,
                                          int& i00, int& i01, int& i10, int& i11,
                                          float& wx, float& wy) {
    xf = fminf(fmaxf(xf, 0.f), (float)(Wn - 1));
    yf = fminf(fmaxf(yf, 0.f), (float)(Hn - 1));
    const float x0f = floorf(xf), y0f = floorf(yf);
    wx = xf - x0f; wy = yf - y0f;
    const int x0 = (int)x0f, y0 = (int)y0f;
    const int x1 = min(x0 + 1, Wn - 1), y1 = min(y0 + 1, Hn - 1);
    i00 = y0 * Wn + x0; i01 = y0 * Wn + x1;
    i10 = y1 * Wn + x0; i11 = y1 * Wn + x1;
}

__device__ __forceinline__ float bilin(const float* __restrict__ base,
                                       int i00, int i01, int i10, int i11,
                                       float wx, float wy) {
    const float v00 = base[i00], v01 = base[i01];
    const float v10 = base[i10], v11 = base[i11];
    const float top = fmaf(wx, v01 - v00, v00);
    const float bot = fmaf(wx, v11 - v10, v10);
    return fmaf(wy, bot - top, top);
}

__global__ __launch_bounds__(256) void warp_loss_kernel(
        const float* __restrict__ L, const float* __restrict__ R,
        const float* __restrict__ Flm, const float* __restrict__ Frm,
        const float* __restrict__ G, double* __restrict__ accum) {
    // XCD k (= bid%8, round-robin dispatch) owns batch image k entirely.
    // it-major chunk order: all 360 blocks of an XCD sweep one contiguous
    // ~72-row band together -> vertical tap overlap stays in that XCD's L2.
    const int b     = blockIdx.x & 7;
    const int inner = blockIdx.x >> 3;

    const float* __restrict__ Lb = L + (size_t)b * Cn * HW;
    const float* __restrict__ Rb = R + (size_t)b * Cn * HW;
    const float* __restrict__ Gb = G + (size_t)b * Cn * HW;
    const float* __restrict__ fl = Flm + (size_t)b * 2 * HW;  // [0,HW)=x, [HW,2HW)=y
    const float* __restrict__ fr = Frm + (size_t)b * 2 * HW;

    float local = 0.f;

    // software pipeline: flow for iteration 0 loaded up front
    int p = inner * BLK + (int)threadIdx.x;
    float lfx = fl[p], lfy = fl[HW + p];
    float rfx = fr[p], rfy = fr[HW + p];

    for (int it = 0; it < ITER; ++it) {
        // issue next iteration's flow loads NOW (overlap with this iteration's
        // gather latency). Clamped address keeps the load always in-bounds.
        const int p_next = min(((it + 1) * NBX + inner) * BLK + (int)threadIdx.x, HW - 1);
        const float nlfx = fl[p_next], nlfy = fl[HW + p_next];
        const float nrfx = fr[p_next], nrfy = fr[HW + p_next];

        const int y = p / Wn;
        const int x = p - y * Wn;

        int   li0, li1, li2, li3, ri0, ri1, ri2, ri3;
        float lwx, lwy, rwx, rwy;
        mk_coords((float)x + lfx, (float)y + lfy, li0, li1, li2, li3, lwx, lwy);
        mk_coords((float)x + rfx, (float)y + rfy, ri0, ri1, ri2, ri3, rwx, rwy);

        #pragma unroll
        for (int c = 0; c < Cn; ++c) {
            const float g  = Gb[c * HW + p];
            const float sL = bilin(Lb + c * HW, li0, li1, li2, li3, lwx, lwy);
            const float sR = bilin(Rb + c * HW, ri0, ri1, ri2, ri3, rwx, rwy);
            local += fabsf(sL - g) + fabsf(sR - g);
        }

        lfx = nlfx; lfy = nlfy; rfx = nrfx; rfy = nrfy;
        p = p_next;
    }

    // wave(64) shuffle reduce -> LDS cross-wave -> one f64 atomic per block
    #pragma unroll
    for (int off = 32; off > 0; off >>= 1)
        local += __shfl_down(local, off, 64);

    __shared__ float wsum[4];
    const int lane = threadIdx.x & 63;
    const int wid  = threadIdx.x >> 6;
    if (lane == 0) wsum[wid] = local;
    __syncthreads();
    if (threadIdx.x == 0) {
        const float s = wsum[0] + wsum[1] + wsum[2] + wsum[3];
        atomicAdd(accum, (double)s);
    }
}

__global__ void finalize_kernel(const double* __restrict__ accum,
                                float* __restrict__ out) {
    out[0] = (float)(accum[0] / (double)NTOT);
}

extern "C" void kernel_launch(void* const* d_in, const int* in_sizes, int n_in,
                              void* d_out, int out_size, void* d_ws, size_t ws_size,
                              hipStream_t stream) {
    const float* L   = (const float*)d_in[0];
    const float* R   = (const float*)d_in[1];
    const float* flm = (const float*)d_in[2];
    const float* frm = (const float*)d_in[3];
    const float* gt  = (const float*)d_in[4];
    double* accum = (double*)d_ws;

    (void)hipMemsetAsync(accum, 0, sizeof(double), stream);
    warp_loss_kernel<<<NWG, BLK, 0, stream>>>(L, R, flm, frm, gt, accum);
    finalize_kernel<<<1, 1, 0, stream>>>(accum, (float*)d_out);
}